// Round 9
// baseline (6233.704 us; speedup 1.0000x reference)
//
#include <hip/hip_runtime.h>
#include <math.h>

#define EPSQ 1e-5f
#define TOK 8192
#define DM 2048
#define DF 8192
#define NW (DM*DF)
#define NGU 16384   // concatenated gate+up output width

typedef float f32x4 __attribute__((ext_vector_type(4)));
typedef int   int32x4 __attribute__((ext_vector_type(4)));
typedef char  i8x4 __attribute__((ext_vector_type(4)));
typedef char  i8x8 __attribute__((ext_vector_type(8)));
typedef _Float16 f16x8 __attribute__((ext_vector_type(8)));

// ---- fixed workspace layout (bytes) ----
#define OFF_DSUM 0ull                                // 3 doubles
#define OFF_SX   (4ull<<10)                          // 8192 f32
#define OFF_SH   (40ull<<10)                         // 8192 f32
#define OFF_XQ   (1ull<<20)                          // 16MB i8 [8192][2048]
#define OFF_WGQ  (OFF_XQ  + (16ull<<20))             // 16MB i8 [8192][2048]
#define OFF_WUQ  (OFF_WGQ + (16ull<<20))             // 16MB (contiguous after WGQ)
#define OFF_WDQ  (OFF_WUQ + (16ull<<20))             // 16MB i8 [2048][8192]
#define OFF_HQ   (OFF_WDQ + (16ull<<20))             // 64MB i8 [8192][8192]
#define FIXED_END (OFF_HQ + (64ull<<20))             // 129MB
// strip region (after FIXED_END): gu fp16 [S][16384]

#define GLL(gp, lp) __builtin_amdgcn_global_load_lds( \
    (const __attribute__((address_space(1))) unsigned int*)(gp), \
    (__attribute__((address_space(3))) unsigned int*)(lp), 16, 0, 0)

// ---- |w| sums for all three weights (absmean scales), f64 totals ----
__global__ void k_wabs3(const float* __restrict__ w0, const float* __restrict__ w1,
                        const float* __restrict__ w2, double* __restrict__ dsum, int n4) {
  const float* w = blockIdx.y == 0 ? w0 : blockIdx.y == 1 ? w1 : w2;
  const f32x4* w4 = (const f32x4*)w;
  float s = 0.f;
  for (int i = blockIdx.x * blockDim.x + threadIdx.x; i < n4; i += gridDim.x * blockDim.x) {
    f32x4 v = w4[i];
    s += fabsf(v.x) + fabsf(v.y) + fabsf(v.z) + fabsf(v.w);
  }
  __shared__ float red[256];
  red[threadIdx.x] = s; __syncthreads();
  for (int o = 128; o > 0; o >>= 1) {
    if (threadIdx.x < o) red[threadIdx.x] += red[threadIdx.x + o];
    __syncthreads();
  }
  if (threadIdx.x == 0) atomicAdd(dsum + blockIdx.y, (double)red[0]);
}

// ---- ternary-quantize all three weights -> int8 {-1,0,1} (contiguous dest) ----
__global__ void k_quant_w3(const float* __restrict__ w0, const float* __restrict__ w1,
                           const float* __restrict__ w2, char* __restrict__ wqall,
                           const double* __restrict__ dsum, int n4) {
  const float* w = blockIdx.y == 0 ? w0 : blockIdx.y == 1 ? w1 : w2;
  char* wq = wqall + (size_t)blockIdx.y * NW;
  float scale = (float)(dsum[blockIdx.y] / (double)NW) + EPSQ;
  const f32x4* w4 = (const f32x4*)w;
  for (int i = blockIdx.x * blockDim.x + threadIdx.x; i < n4; i += gridDim.x * blockDim.x) {
    f32x4 v = w4[i];
    i8x4 o;
#pragma unroll
    for (int c = 0; c < 4; c++) {
      float q = rintf(v[c] / scale);
      q = fminf(1.f, fmaxf(-1.f, q));
      o[c] = (char)(int)q;
    }
    *(i8x4*)&wq[(size_t)i * 4] = o;
  }
}

// ---- per-token int8 quantize x -> int8 + scale ----
__global__ void k_quant_x(const float* __restrict__ x, char* __restrict__ xq,
                          float* __restrict__ sx) {
  const int row = blockIdx.x;
  const int tid = threadIdx.x;
  const f32x4* xr = (const f32x4*)(x + (size_t)row * DM);
  f32x4 v0 = xr[tid * 2], v1 = xr[tid * 2 + 1];
  float m = 0.f;
#pragma unroll
  for (int c = 0; c < 4; c++) m = fmaxf(m, fmaxf(fabsf(v0[c]), fabsf(v1[c])));
  __shared__ float red[256];
  red[tid] = m; __syncthreads();
  for (int o = 128; o > 0; o >>= 1) {
    if (tid < o) red[tid] = fmaxf(red[tid], red[tid + o]);
    __syncthreads();
  }
  float sc = fmaxf(red[0], EPSQ) / 127.f;
  if (tid == 0) sx[row] = sc;
  i8x8 o;
#pragma unroll
  for (int c = 0; c < 4; c++) {
    float q0 = fminf(127.f, fmaxf(-128.f, rintf(v0[c] / sc)));
    float q1 = fminf(127.f, fmaxf(-128.f, rintf(v1[c] / sc)));
    o[c] = (char)(int)q0; o[c + 4] = (char)(int)q1;
  }
  *(i8x8*)&xq[(size_t)row * DM + tid * 8] = o;
}

// ---- fused h = sigmoid(gate)*up (fp16 gu in), row-max, int8 quantize ----
__global__ void k_gufuse(const _Float16* __restrict__ gu, char* __restrict__ hq,
                         float* __restrict__ sh) {
  const int row = blockIdx.x;
  const int tid = threadIdx.x;
  const f16x8* g8 = (const f16x8*)(gu + (size_t)row * NGU);
  const f16x8* u8 = g8 + (DF / 8);
  float h[32];
  float m = 0.f;
#pragma unroll
  for (int j = 0; j < 4; j++) {
    f16x8 gg = g8[tid * 4 + j];
    f16x8 uu = u8[tid * 4 + j];
#pragma unroll
    for (int c = 0; c < 8; c++) {
      float v = (float)uu[c] / (1.f + expf(-(float)gg[c]));   // sigmoid(g)*u
      h[j * 8 + c] = v;
      m = fmaxf(m, fabsf(v));
    }
  }
  __shared__ float red[256];
  red[tid] = m; __syncthreads();
  for (int o = 128; o > 0; o >>= 1) {
    if (tid < o) red[tid] = fmaxf(red[tid], red[tid + o]);
    __syncthreads();
  }
  float sc = fmaxf(red[0], EPSQ) / 127.f;
  if (tid == 0) sh[row] = sc;
#pragma unroll
  for (int jj = 0; jj < 4; jj++) {
    i8x8 o;
#pragma unroll
    for (int c = 0; c < 8; c++) {
      float q = fminf(127.f, fmaxf(-128.f, rintf(h[jj * 8 + c] / sc)));
      o[c] = (char)(int)q;
    }
    *(i8x8*)&hq[(size_t)row * DF + tid * 32 + jj * 8] = o;
  }
}

// ---- 256x256-tile i8 MFMA GEMM, 4-deep ring of BK=64 sub-tiles,
//      register frag double-buffer + WAVE ROLE-STAGGER: odd waves run
//      {MFMA; reads}, even waves {reads; MFMA}, so LDS port and matrix pipes
//      stay concurrently busy across the CU (breaks the post-barrier convoy).
//      T4 counted vmcnt (distance-3 prefetch), T2 swizzle via pre-swizzled GLL
//      source, T5 setprio, T1 XCD swizzle.
// C[m,n] = (sum_k A[m,k]*B[n,k]) * rowscale[m] * sw,  sw selected by n0 vs colsplit.
template<typename OT>
__global__ __launch_bounds__(512, 2)
void k_gemm8(const char* __restrict__ A, const char* __restrict__ B,
             OT* __restrict__ C, const float* __restrict__ rowscale,
             const double* __restrict__ dsumA, const double* __restrict__ dsumB,
             int colsplit, int N, int K) {
  // ring of 4 sub-tiles; each: A 256x64 i8 (16KB) + B 256x64 i8 (16KB)
  __shared__ __align__(16) char sm[4][2][16384];

  const int tid = threadIdx.x;
  const int wv = tid >> 6;          // 0..7
  const int lane = tid & 63;
  const int wm = wv >> 2;           // 0..1  (M half: 128 rows)
  const int wn = wv & 3;            // 0..3  (N quarter: 64 cols)
  const int lr = lane & 15;
  const int g = lane >> 4;          // 0..3  (16B k-slot group)
  const int c3 = (lr >> 1) & 3;     // read-side slot swizzle key

  // bijective XCD swizzle (nwg % 8 == 0 for all our grids)
  const int nwg = gridDim.x * gridDim.y;
  const int bid = blockIdx.y * gridDim.x + blockIdx.x;
  const int lid = (bid & 7) * (nwg >> 3) + (bid >> 3);
  const int gx = N >> 8;
  const int n0 = (lid % gx) << 8;
  const int m0 = (lid / gx) << 8;

  const float sw = (n0 < colsplit)
      ? (float)(*dsumA / (double)NW) + EPSQ
      : (float)(*dsumB / (double)NW) + EPSQ;

  // staging: one GLL = 1KB = 16 rows x 64B. wave wv stages rows [wv*32, wv*32+32):
  // LDS dest linear; source col pre-swizzled: slot = (l&3) ^ ((l>>3)&3).
  const int srow = lane >> 2;                       // 0..15
  const int sslot = (lane & 3) ^ ((lane >> 3) & 3); // pre-swizzled 16B slot
  const char* gA0 = A + (size_t)(m0 + wv * 32 + srow) * K + sslot * 16;
  const char* gA1 = gA0 + (size_t)16 * K;
  const char* gB0 = B + (size_t)(n0 + wv * 32 + srow) * K + sslot * 16;
  const char* gB1 = gB0 + (size_t)16 * K;
  const int dst0 = (wv * 32) * 64 + lane * 16;      // byte offset in 16KB plane
  const int dst1 = dst0 + 1024;

#define STAGE(s) do { \
    const size_t ko_ = (size_t)(s) * 64; \
    char* pA_ = &sm[(s) & 3][0][0]; \
    char* pB_ = &sm[(s) & 3][1][0]; \
    GLL(gA0 + ko_, pA_ + dst0); \
    GLL(gA1 + ko_, pA_ + dst1); \
    GLL(gB0 + ko_, pB_ + dst0); \
    GLL(gB1 + ko_, pB_ + dst1); \
  } while (0)

  int32x4 acc[8][4];
  const int32x4 z4 = {0, 0, 0, 0};
#pragma unroll
  for (int m = 0; m < 8; m++)
#pragma unroll
    for (int n = 0; n < 4; n++) acc[m][n] = z4;

  const int NS = K >> 6;   // sub-tiles of 64 (always even: K multiple of 128)
  const int abase = (wm * 128 + lr) * 64 + ((g ^ c3) << 4);
  const int bbase = (wn * 64 + lr) * 64 + ((g ^ c3) << 4);

  // prologue: stage 0,1,2 (12 loads); wait sub-tile 0; load cur frags
  STAGE(0); STAGE(1); STAGE(2);
  asm volatile("s_waitcnt vmcnt(8)" ::: "memory");
  __builtin_amdgcn_s_barrier();

  int32x4 curA[8], curB[4], nxtA[8], nxtB[4];
  {
    const char* smA = &sm[0][0][0];
    const char* smB = &sm[0][1][0];
#pragma unroll
    for (int n = 0; n < 4; n++) curB[n] = *(const int32x4*)&smB[bbase + n * 1024];
#pragma unroll
    for (int m = 0; m < 8; m++) curA[m] = *(const int32x4*)&smA[abase + m * 1024];
  }

#define READS(NA, NB, slot_) do { \
    const char* smA_ = &sm[(slot_)][0][0]; \
    const char* smB_ = &sm[(slot_)][1][0]; \
    _Pragma("unroll") \
    for (int n = 0; n < 4; n++) NB[n] = *(const int32x4*)&smB_[bbase + n * 1024]; \
    _Pragma("unroll") \
    for (int m = 0; m < 8; m++) NA[m] = *(const int32x4*)&smA_[abase + m * 1024]; \
  } while (0)

#define MFMAS(CA, CB) do { \
    __builtin_amdgcn_s_setprio(1); \
    _Pragma("unroll") \
    for (int m = 0; m < 8; m++) \
      _Pragma("unroll") \
      for (int n = 0; n < 4; n++) \
        acc[m][n] = __builtin_amdgcn_mfma_i32_16x16x64_i8(CA[m], CB[n], acc[m][n], 0, 0, 0); \
    __builtin_amdgcn_s_setprio(0); \
  } while (0)

  // pipelined iteration: stage s+3, wait s staged, then role-staggered
  // {reads(s+1) ; MFMA(s)} vs {MFMA(s) ; reads(s+1)} per wave parity.
#define ITER(sv, CA, CB, NA, NB) do { \
    const int s_ = (sv); \
    const int ahead_ = NS - 1 - s_; \
    if (ahead_ >= 3) { \
      STAGE(s_ + 3); \
      asm volatile("s_waitcnt vmcnt(8)" ::: "memory"); \
    } else if (ahead_ == 2) { \
      asm volatile("s_waitcnt vmcnt(4)" ::: "memory"); \
    } else { \
      asm volatile("s_waitcnt vmcnt(0)" ::: "memory"); \
    } \
    asm volatile("s_waitcnt lgkmcnt(0)" ::: "memory"); \
    __builtin_amdgcn_s_barrier(); \
    if (wv & 1) { \
      MFMAS(CA, CB); \
      __builtin_amdgcn_sched_barrier(0); \
      READS(NA, NB, (s_ + 1) & 3); \
    } else { \
      READS(NA, NB, (s_ + 1) & 3); \
      __builtin_amdgcn_sched_barrier(0); \
      MFMAS(CA, CB); \
    } \
  } while (0)

  // NS even -> NS-1 (odd) pipelined iterations + peeled final compute
  for (int s = 0; s + 1 < NS - 1; s += 2) {
    ITER(s, curA, curB, nxtA, nxtB);
    ITER(s + 1, nxtA, nxtB, curA, curB);
  }
  ITER(NS - 2, curA, curB, nxtA, nxtB);

  asm volatile("s_waitcnt lgkmcnt(0)" ::: "memory");
  __builtin_amdgcn_sched_barrier(0);
  MFMAS(nxtA, nxtB);
#undef ITER
#undef READS
#undef MFMAS
#undef STAGE

  // epilogue: C/D layout col = lane&15, row = (lane>>4)*4 + j
#pragma unroll
  for (int m = 0; m < 8; m++) {
#pragma unroll
    for (int j = 0; j < 4; j++) {
      const int row = m0 + wm * 128 + m * 16 + g * 4 + j;
      const float rs = rowscale[row] * sw;
#pragma unroll
      for (int n = 0; n < 4; n++) {
        const int col = n0 + wn * 64 + n * 16 + lr;
        C[(size_t)row * N + col] = (OT)((float)acc[m][n][j] * rs);
      }
    }
  }
}

extern "C" void kernel_launch(void* const* d_in, const int* in_sizes, int n_in,
                              void* d_out, int out_size, void* d_ws, size_t ws_size,
                              hipStream_t stream) {
  const float* x  = (const float*)d_in[0];
  const float* wg = (const float*)d_in[1];
  const float* wu = (const float*)d_in[2];
  const float* wd = (const float*)d_in[3];
  float* out = (float*)d_out;
  char* ws = (char*)d_ws;

  double* dsum = (double*)(ws + OFF_DSUM);
  float* sx = (float*)(ws + OFF_SX);
  float* sh = (float*)(ws + OFF_SH);
  char* xq  = ws + OFF_XQ;
  char* wgq = ws + OFF_WGQ;   // wgq..wuq contiguous = [16384][2048]
  char* wdq = ws + OFF_WDQ;
  char* hq  = ws + OFF_HQ;    // full [8192][8192] int8

  // strip sizing: per row need 16384*2 B (gu fp16); S multiple of 256
  size_t avail = ws_size > FIXED_END ? ws_size - FIXED_END : 0;
  int S = 256;
  for (int cand = 8192; cand >= 256; cand >>= 1) {
    if ((size_t)cand * 32768ull <= avail) { S = cand; break; }
  }
  _Float16* gubuf = (_Float16*)(ws + FIXED_END);

  hipMemsetAsync(ws, 0, 64, stream);

  const int n4 = NW / 4;
  k_wabs3<<<dim3(2048, 3), 256, 0, stream>>>(wg, wu, wd, dsum, n4);
  k_quant_w3<<<dim3(2048, 3), 256, 0, stream>>>(wg, wu, wd, wgq, dsum, n4);
  k_quant_x<<<TOK, 256, 0, stream>>>(x, xq, sx);

  for (int base = 0; base < TOK; base += S) {
    // [gate | up] = xq_strip @ [wgq; wuq]^T  (N = 16384, fp16 out)
    k_gemm8<_Float16><<<dim3(NGU / 256, S / 256), 512, 0, stream>>>(
        xq + (size_t)base * DM, wgq, gubuf, sx + base,
        dsum + 0, dsum + 1, DF, NGU, DM);

    k_gufuse<<<S, 256, 0, stream>>>(gubuf, hq + (size_t)base * DF, sh + base);
  }

  // single down-projection GEMM over all rows (fp32 out)
  k_gemm8<float><<<dim3(DM / 256, TOK / 256), 512, 0, stream>>>(
      hq, wdq, out, sh, dsum + 2, dsum + 2, 1 << 30, DM, DF);
}

// Round 10
// 673.652 us; speedup vs baseline: 9.2536x; 9.2536x over previous
//
#include <hip/hip_runtime.h>
#include <math.h>

#define EPSQ 1e-5f
#define TOK 8192
#define DM 2048
#define DF 8192
#define NW (DM*DF)
#define NGU 16384   // concatenated gate+up output width

typedef float f32x4 __attribute__((ext_vector_type(4)));
typedef int   int32x4 __attribute__((ext_vector_type(4)));
typedef char  i8x4 __attribute__((ext_vector_type(4)));
typedef char  i8x8 __attribute__((ext_vector_type(8)));
typedef _Float16 f16x8 __attribute__((ext_vector_type(8)));

// ---- fixed workspace layout (bytes) ----
#define OFF_DSUM 0ull                                // 3 doubles
#define OFF_SX   (4ull<<10)                          // 8192 f32
#define OFF_SH   (40ull<<10)                         // 8192 f32
#define OFF_XQ   (1ull<<20)                          // 16MB i8 [8192][2048]
#define OFF_WGQ  (OFF_XQ  + (16ull<<20))             // 16MB i8 [8192][2048]
#define OFF_WUQ  (OFF_WGQ + (16ull<<20))             // 16MB (contiguous after WGQ)
#define OFF_WDQ  (OFF_WUQ + (16ull<<20))             // 16MB i8 [2048][8192]
#define OFF_HQ   (OFF_WDQ + (16ull<<20))             // 64MB i8 [8192][8192]
#define FIXED_END (OFF_HQ + (64ull<<20))             // 129MB
// strip region (after FIXED_END): gu fp16 [S][16384]

#define GLL(gp, lp) __builtin_amdgcn_global_load_lds( \
    (const __attribute__((address_space(1))) unsigned int*)(gp), \
    (__attribute__((address_space(3))) unsigned int*)(lp), 16, 0, 0)

// ---- |w| sums for all three weights (absmean scales), f64 totals ----
__global__ void k_wabs3(const float* __restrict__ w0, const float* __restrict__ w1,
                        const float* __restrict__ w2, double* __restrict__ dsum, int n4) {
  const float* w = blockIdx.y == 0 ? w0 : blockIdx.y == 1 ? w1 : w2;
  const f32x4* w4 = (const f32x4*)w;
  float s = 0.f;
  for (int i = blockIdx.x * blockDim.x + threadIdx.x; i < n4; i += gridDim.x * blockDim.x) {
    f32x4 v = w4[i];
    s += fabsf(v.x) + fabsf(v.y) + fabsf(v.z) + fabsf(v.w);
  }
  __shared__ float red[256];
  red[threadIdx.x] = s; __syncthreads();
  for (int o = 128; o > 0; o >>= 1) {
    if (threadIdx.x < o) red[threadIdx.x] += red[threadIdx.x + o];
    __syncthreads();
  }
  if (threadIdx.x == 0) atomicAdd(dsum + blockIdx.y, (double)red[0]);
}

// ---- ternary-quantize all three weights -> int8 {-1,0,1} (contiguous dest) ----
__global__ void k_quant_w3(const float* __restrict__ w0, const float* __restrict__ w1,
                           const float* __restrict__ w2, char* __restrict__ wqall,
                           const double* __restrict__ dsum, int n4) {
  const float* w = blockIdx.y == 0 ? w0 : blockIdx.y == 1 ? w1 : w2;
  char* wq = wqall + (size_t)blockIdx.y * NW;
  float scale = (float)(dsum[blockIdx.y] / (double)NW) + EPSQ;
  const f32x4* w4 = (const f32x4*)w;
  for (int i = blockIdx.x * blockDim.x + threadIdx.x; i < n4; i += gridDim.x * blockDim.x) {
    f32x4 v = w4[i];
    i8x4 o;
#pragma unroll
    for (int c = 0; c < 4; c++) {
      float q = rintf(v[c] / scale);
      q = fminf(1.f, fmaxf(-1.f, q));
      o[c] = (char)(int)q;
    }
    *(i8x4*)&wq[(size_t)i * 4] = o;
  }
}

// ---- per-token int8 quantize x -> int8 + scale ----
__global__ void k_quant_x(const float* __restrict__ x, char* __restrict__ xq,
                          float* __restrict__ sx) {
  const int row = blockIdx.x;
  const int tid = threadIdx.x;
  const f32x4* xr = (const f32x4*)(x + (size_t)row * DM);
  f32x4 v0 = xr[tid * 2], v1 = xr[tid * 2 + 1];
  float m = 0.f;
#pragma unroll
  for (int c = 0; c < 4; c++) m = fmaxf(m, fmaxf(fabsf(v0[c]), fabsf(v1[c])));
  __shared__ float red[256];
  red[tid] = m; __syncthreads();
  for (int o = 128; o > 0; o >>= 1) {
    if (tid < o) red[tid] = fmaxf(red[tid], red[tid + o]);
    __syncthreads();
  }
  float sc = fmaxf(red[0], EPSQ) / 127.f;
  if (tid == 0) sx[row] = sc;
  i8x8 o;
#pragma unroll
  for (int c = 0; c < 4; c++) {
    float q0 = fminf(127.f, fmaxf(-128.f, rintf(v0[c] / sc)));
    float q1 = fminf(127.f, fmaxf(-128.f, rintf(v1[c] / sc)));
    o[c] = (char)(int)q0; o[c + 4] = (char)(int)q1;
  }
  *(i8x8*)&xq[(size_t)row * DM + tid * 8] = o;
}

// ---- fused h = sigmoid(gate)*up (fp16 gu in), row-max, int8 quantize ----
__global__ void k_gufuse(const _Float16* __restrict__ gu, char* __restrict__ hq,
                         float* __restrict__ sh) {
  const int row = blockIdx.x;
  const int tid = threadIdx.x;
  const f16x8* g8 = (const f16x8*)(gu + (size_t)row * NGU);
  const f16x8* u8 = g8 + (DF / 8);
  float h[32];
  float m = 0.f;
#pragma unroll
  for (int j = 0; j < 4; j++) {
    f16x8 gg = g8[tid * 4 + j];
    f16x8 uu = u8[tid * 4 + j];
#pragma unroll
    for (int c = 0; c < 8; c++) {
      float v = (float)uu[c] / (1.f + expf(-(float)gg[c]));   // sigmoid(g)*u
      h[j * 8 + c] = v;
      m = fmaxf(m, fabsf(v));
    }
  }
  __shared__ float red[256];
  red[tid] = m; __syncthreads();
  for (int o = 128; o > 0; o >>= 1) {
    if (tid < o) red[tid] = fmaxf(red[tid], red[tid + o]);
    __syncthreads();
  }
  float sc = fmaxf(red[0], EPSQ) / 127.f;
  if (tid == 0) sh[row] = sc;
#pragma unroll
  for (int jj = 0; jj < 4; jj++) {
    i8x8 o;
#pragma unroll
    for (int c = 0; c < 8; c++) {
      float q = fminf(127.f, fmaxf(-128.f, rintf(h[jj * 8 + c] / sc)));
      o[c] = (char)(int)q;
    }
    *(i8x8*)&hq[(size_t)row * DF + tid * 32 + jj * 8] = o;
  }
}

// ---- 256x256-tile i8 MFMA GEMM, 4-deep ring of BK=64 sub-tiles,
//      register frag double-buffer; per-wave DS_READ/MFMA interleave via
//      sched_group_barrier (T19/AITER pattern) so the LDS FIFO never blocks
//      in-order issue against the MFMA cluster. Uniform control flow (r9
//      lesson: divergent pipeline duplication spills to scratch).
//      T4 counted vmcnt (distance-3 prefetch), T2 swizzle via pre-swizzled GLL
//      source, T5 setprio, T1 XCD swizzle.
// C[m,n] = (sum_k A[m,k]*B[n,k]) * rowscale[m] * sw,  sw selected by n0 vs colsplit.
template<typename OT>
__global__ __launch_bounds__(512, 2)
void k_gemm8(const char* __restrict__ A, const char* __restrict__ B,
             OT* __restrict__ C, const float* __restrict__ rowscale,
             const double* __restrict__ dsumA, const double* __restrict__ dsumB,
             int colsplit, int N, int K) {
  // ring of 4 sub-tiles; each: A 256x64 i8 (16KB) + B 256x64 i8 (16KB)
  __shared__ __align__(16) char sm[4][2][16384];

  const int tid = threadIdx.x;
  const int wv = tid >> 6;          // 0..7
  const int lane = tid & 63;
  const int wm = wv >> 2;           // 0..1  (M half: 128 rows)
  const int wn = wv & 3;            // 0..3  (N quarter: 64 cols)
  const int lr = lane & 15;
  const int g = lane >> 4;          // 0..3  (16B k-slot group)
  const int c3 = (lr >> 1) & 3;     // read-side slot swizzle key

  // bijective XCD swizzle (nwg % 8 == 0 for all our grids)
  const int nwg = gridDim.x * gridDim.y;
  const int bid = blockIdx.y * gridDim.x + blockIdx.x;
  const int lid = (bid & 7) * (nwg >> 3) + (bid >> 3);
  const int gx = N >> 8;
  const int n0 = (lid % gx) << 8;
  const int m0 = (lid / gx) << 8;

  const float sw = (n0 < colsplit)
      ? (float)(*dsumA / (double)NW) + EPSQ
      : (float)(*dsumB / (double)NW) + EPSQ;

  // staging: one GLL = 1KB = 16 rows x 64B. wave wv stages rows [wv*32, wv*32+32):
  // LDS dest linear; source col pre-swizzled: slot = (l&3) ^ ((l>>3)&3).
  const int srow = lane >> 2;                       // 0..15
  const int sslot = (lane & 3) ^ ((lane >> 3) & 3); // pre-swizzled 16B slot
  const char* gA0 = A + (size_t)(m0 + wv * 32 + srow) * K + sslot * 16;
  const char* gA1 = gA0 + (size_t)16 * K;
  const char* gB0 = B + (size_t)(n0 + wv * 32 + srow) * K + sslot * 16;
  const char* gB1 = gB0 + (size_t)16 * K;
  const int dst0 = (wv * 32) * 64 + lane * 16;      // byte offset in 16KB plane
  const int dst1 = dst0 + 1024;

#define STAGE(s) do { \
    const size_t ko_ = (size_t)(s) * 64; \
    char* pA_ = &sm[(s) & 3][0][0]; \
    char* pB_ = &sm[(s) & 3][1][0]; \
    GLL(gA0 + ko_, pA_ + dst0); \
    GLL(gA1 + ko_, pA_ + dst1); \
    GLL(gB0 + ko_, pB_ + dst0); \
    GLL(gB1 + ko_, pB_ + dst1); \
  } while (0)

  int32x4 acc[8][4];
  const int32x4 z4 = {0, 0, 0, 0};
#pragma unroll
  for (int m = 0; m < 8; m++)
#pragma unroll
    for (int n = 0; n < 4; n++) acc[m][n] = z4;

  const int NS = K >> 6;   // sub-tiles of 64 (always even: K multiple of 128)
  const int abase = (wm * 128 + lr) * 64 + ((g ^ c3) << 4);
  const int bbase = (wn * 64 + lr) * 64 + ((g ^ c3) << 4);

  // prologue: stage 0,1,2 (12 loads); wait sub-tile 0; load cur frags
  STAGE(0); STAGE(1); STAGE(2);
  asm volatile("s_waitcnt vmcnt(8)" ::: "memory");
  __builtin_amdgcn_s_barrier();

  int32x4 curA[8], curB[4], nxtA[8], nxtB[4];
  {
    const char* smA = &sm[0][0][0];
    const char* smB = &sm[0][1][0];
#pragma unroll
    for (int n = 0; n < 4; n++) curB[n] = *(const int32x4*)&smB[bbase + n * 1024];
#pragma unroll
    for (int m = 0; m < 8; m++) curA[m] = *(const int32x4*)&smA[abase + m * 1024];
  }

#define READS(NA, NB, slot_) do { \
    const char* smA_ = &sm[(slot_)][0][0]; \
    const char* smB_ = &sm[(slot_)][1][0]; \
    _Pragma("unroll") \
    for (int n = 0; n < 4; n++) NB[n] = *(const int32x4*)&smB_[bbase + n * 1024]; \
    _Pragma("unroll") \
    for (int m = 0; m < 8; m++) NA[m] = *(const int32x4*)&smA_[abase + m * 1024]; \
  } while (0)

#define MFMAS(CA, CB) do { \
    _Pragma("unroll") \
    for (int m = 0; m < 8; m++) \
      _Pragma("unroll") \
      for (int n = 0; n < 4; n++) \
        acc[m][n] = __builtin_amdgcn_mfma_i32_16x16x64_i8(CA[m], CB[n], acc[m][n], 0, 0, 0); \
  } while (0)

  // interleave directive: {2 ds_read, 5 mfma} x6 + {2 mfma}  (12 reads, 32 mfma)
#define INTERLEAVE() do { \
    _Pragma("unroll") \
    for (int gg = 0; gg < 6; gg++) { \
      __builtin_amdgcn_sched_group_barrier(0x100, 2, 0); \
      __builtin_amdgcn_sched_group_barrier(0x008, 5, 0); \
    } \
    __builtin_amdgcn_sched_group_barrier(0x008, 2, 0); \
  } while (0)

  // pipelined iteration: stage s+3, wait s staged, read frags(s+1) into NXT
  // interleaved with MFMA(s) on CUR (disjoint registers; uniform flow).
#define ITER(sv, CA, CB, NA, NB) do { \
    const int s_ = (sv); \
    const int ahead_ = NS - 1 - s_; \
    if (ahead_ >= 3) { \
      STAGE(s_ + 3); \
      asm volatile("s_waitcnt vmcnt(8)" ::: "memory"); \
    } else if (ahead_ == 2) { \
      asm volatile("s_waitcnt vmcnt(4)" ::: "memory"); \
    } else { \
      asm volatile("s_waitcnt vmcnt(0)" ::: "memory"); \
    } \
    asm volatile("s_waitcnt lgkmcnt(0)" ::: "memory"); \
    __builtin_amdgcn_sched_barrier(0); \
    __builtin_amdgcn_s_barrier(); \
    __builtin_amdgcn_s_setprio(1); \
    READS(NA, NB, (s_ + 1) & 3); \
    MFMAS(CA, CB); \
    INTERLEAVE(); \
    __builtin_amdgcn_s_setprio(0); \
  } while (0)

  // NS even -> NS-1 (odd) pipelined iterations + peeled final compute
  for (int s = 0; s + 1 < NS - 1; s += 2) {
    ITER(s, curA, curB, nxtA, nxtB);
    ITER(s + 1, nxtA, nxtB, curA, curB);
  }
  ITER(NS - 2, curA, curB, nxtA, nxtB);

  asm volatile("s_waitcnt lgkmcnt(0)" ::: "memory");
  __builtin_amdgcn_sched_barrier(0);
  __builtin_amdgcn_s_setprio(1);
  MFMAS(nxtA, nxtB);
  __builtin_amdgcn_s_setprio(0);
#undef ITER
#undef INTERLEAVE
#undef READS
#undef MFMAS
#undef STAGE

  // epilogue: C/D layout col = lane&15, row = (lane>>4)*4 + j
#pragma unroll
  for (int m = 0; m < 8; m++) {
#pragma unroll
    for (int j = 0; j < 4; j++) {
      const int row = m0 + wm * 128 + m * 16 + g * 4 + j;
      const float rs = rowscale[row] * sw;
#pragma unroll
      for (int n = 0; n < 4; n++) {
        const int col = n0 + wn * 64 + n * 16 + lr;
        C[(size_t)row * N + col] = (OT)((float)acc[m][n][j] * rs);
      }
    }
  }
}

extern "C" void kernel_launch(void* const* d_in, const int* in_sizes, int n_in,
                              void* d_out, int out_size, void* d_ws, size_t ws_size,
                              hipStream_t stream) {
  const float* x  = (const float*)d_in[0];
  const float* wg = (const float*)d_in[1];
  const float* wu = (const float*)d_in[2];
  const float* wd = (const float*)d_in[3];
  float* out = (float*)d_out;
  char* ws = (char*)d_ws;

  double* dsum = (double*)(ws + OFF_DSUM);
  float* sx = (float*)(ws + OFF_SX);
  float* sh = (float*)(ws + OFF_SH);
  char* xq  = ws + OFF_XQ;
  char* wgq = ws + OFF_WGQ;   // wgq..wuq contiguous = [16384][2048]
  char* wdq = ws + OFF_WDQ;
  char* hq  = ws + OFF_HQ;    // full [8192][8192] int8

  // strip sizing: per row need 16384*2 B (gu fp16); S multiple of 256
  size_t avail = ws_size > FIXED_END ? ws_size - FIXED_END : 0;
  int S = 256;
  for (int cand = 8192; cand >= 256; cand >>= 1) {
    if ((size_t)cand * 32768ull <= avail) { S = cand; break; }
  }
  _Float16* gubuf = (_Float16*)(ws + FIXED_END);

  hipMemsetAsync(ws, 0, 64, stream);

  const int n4 = NW / 4;
  k_wabs3<<<dim3(2048, 3), 256, 0, stream>>>(wg, wu, wd, dsum, n4);
  k_quant_w3<<<dim3(2048, 3), 256, 0, stream>>>(wg, wu, wd, wgq, dsum, n4);
  k_quant_x<<<TOK, 256, 0, stream>>>(x, xq, sx);

  for (int base = 0; base < TOK; base += S) {
    // [gate | up] = xq_strip @ [wgq; wuq]^T  (N = 16384, fp16 out)
    k_gemm8<_Float16><<<dim3(NGU / 256, S / 256), 512, 0, stream>>>(
        xq + (size_t)base * DM, wgq, gubuf, sx + base,
        dsum + 0, dsum + 1, DF, NGU, DM);

    k_gufuse<<<S, 256, 0, stream>>>(gubuf, hq + (size_t)base * DF, sh + base);
  }

  // single down-projection GEMM over all rows (fp32 out)
  k_gemm8<float><<<dim3(DM / 256, TOK / 256), 512, 0, stream>>>(
      hq, wdq, out, sh, dsum + 2, dsum + 2, 1 << 30, DM, DF);
}